// Round 1
// baseline (206.471 us; speedup 1.0000x reference)
//
#include <hip/hip_runtime.h>
#include <math.h>

#define NP 50000
#define CH 64
#define KMAX 64
#define KNN 16
#define NB 25
#define PTS (NP / NB)            // 2000
#define EPSF 1e-16f
#define NTILES (NP / 16)         // 3125 (16-node tiles for qkv)
#define ATILES (NP / 4)          // 12500 (4-node tiles for attn)
#define L2E 1.4426950408889634f
#define LN2 0.6931471805599453f
#define PPB 8                    // pool partials per cloud
#define PROWS (PTS / PPB)        // 250

typedef __attribute__((ext_vector_type(8))) short short8;
typedef __attribute__((ext_vector_type(4))) float float4v;
typedef __attribute__((ext_vector_type(4))) unsigned int uint4v;
typedef __attribute__((ext_vector_type(2))) unsigned int uint2v;
typedef __attribute__((ext_vector_type(4))) unsigned short ushort4v;

__device__ __forceinline__ ushort f2b(float f) {
  unsigned u = __float_as_uint(f);
  unsigned r = (u + 0x7FFFu + ((u >> 16) & 1u)) >> 16;
  return (ushort)r;
}
__device__ __forceinline__ float b2f(ushort h) {
  return __uint_as_float(((unsigned)h) << 16);
}

// ws layout (bytes):
//   qbf  : 3 * NP * CH * 2   (bf16, log2e-scaled Q)
//   kvp  : 3 * NP * CH * 4   (packed dword: K_s bf16 hi | V bf16 lo)
//   wpack: 36864 ushort (A-frag layout; Q,K pre-scaled by log2e)
//   poolP: NB * PPB * CH fp32 (per-cloud pool partials)
#define QBF_BYTES   ((size_t)3 * NP * CH * 2)
#define KVP_BYTES   ((size_t)3 * NP * CH * 4)
#define WPACK_ELEMS (9 * 4 * 2 * 64 * 8)

// Per-(half,dd) list of the 8 compacted-slot indices this wave walks.
// slots 0-15 = edges 0-15; 16-23 = edges 16,18..30; 24-31 = edges 32,36..60.
// index = wy = half*3+dd, bytes little-endian = e0..e7.
__device__ const unsigned long long SLOTQ[6] = {
    0x0706050403020100ULL,   // dd0 h0: 0..7
    0x0E0C0A0806040200ULL,   // dd1 h0: 0,2,..,14
    0x161412100C080400ULL,   // dd2 h0: 0,4,8,12,16,18,20,22
    0x0F0E0D0C0B0A0908ULL,   // dd0 h1: 8..15
    0x1716151413121110ULL,   // dd1 h1: 16..23
    0x1F1E1D1C1B1A1918ULL};  // dd2 h1: 24..31

// ---------------------------------------------------------------------------
// Kernel 0: prep = pool partials (blocks 0..NB*PPB-1) + W pack.
// (x->bf16 conversion moved into qkv_mfma; x_bf intermediate eliminated.)
// ---------------------------------------------------------------------------
__global__ __launch_bounds__(256) void prep_kernel(
    const float* __restrict__ x,
    const float* __restrict__ Wv,
    const float* __restrict__ Wq,
    const float* __restrict__ Wk,
    ushort* __restrict__ wpack,
    float* __restrict__ poolP) {
  const int tid = threadIdx.x;
  const int bid = blockIdx.x;
  __shared__ float red[4][CH];

  if (bid < NB * PPB) {                 // ---- pool partial path ----
    const int lane = tid & 63;
    const int wave = tid >> 6;
    const int cloud = bid >> 3;
    const int part  = bid & 7;
    const float* xb = x + ((size_t)cloud * PTS + part * PROWS) * CH;
    float m0 = -INFINITY, m1 = -INFINITY;
    for (int r = wave * 2; r < PROWS; r += 8) {
      m0 = fmaxf(m0, xb[(size_t)(r + 0) * CH + lane]);
      m1 = fmaxf(m1, xb[(size_t)(r + 1) * CH + lane]);
    }
    red[wave][lane] = fmaxf(m0, m1);
    __syncthreads();
    if (wave == 0) {
      poolP[(size_t)bid * CH + lane] = fmaxf(fmaxf(red[0][lane], red[1][lane]),
                                             fmaxf(red[2][lane], red[3][lane]));
    }
  } else {                              // ---- W pack path ----
    int pid = (bid - NB * PPB) * 256 + tid;
    if (pid < WPACK_ELEMS) {
      int j     = pid & 7;
      int lane  = (pid >> 3) & 63;
      int kstep = (pid >> 9) & 1;
      int mtile = (pid >> 10) & 3;
      int mat   = pid >> 12;
      const float* W;
      int d;
      float scale;
      if (mat < 3)      { W = Wq; d = mat;     scale = L2E; }
      else if (mat < 6) { W = Wk; d = mat - 3; scale = L2E; }
      else              { W = Wv; d = mat - 6; scale = 1.f; }
      int oc = mtile * 16 + (lane & 15);
      int ic = kstep * 32 + ((lane >> 4) & 3) * 8 + j;
      wpack[pid] = f2b(W[d * CH * CH + ic * CH + oc] * scale);
    }
  }
}

// ---------------------------------------------------------------------------
// Kernel 1: projections via MFMA 16x16x32 bf16. Single pass: each wave owns
// one 16-node tile, converts x f32->bf16 in-register, computes ALL 9
// projections (Q/K/V x 3 dilations = 72 MFMAs). x read ONCE (was 6x).
// D lane: node=lane&15, oc=mt*16+(lane>>4)*4+reg.
// ---------------------------------------------------------------------------
__global__ __launch_bounds__(256) void qkv_mfma(
    const float* __restrict__ x,
    const ushort* __restrict__ wpack,
    ushort* __restrict__ qbf,
    unsigned int* __restrict__ kvp) {
  const int lane = threadIdx.x;
  const int tile = blockIdx.x * 4 + threadIdx.y;
  if (tile >= NTILES) return;
  const int kbase = (lane >> 4) * 8;
  const int myNode = tile * 16 + (lane & 15);
  const float* xr = x + (size_t)myNode * CH;

  float4v xa = *(const float4v*)(xr + kbase);
  float4v xb = *(const float4v*)(xr + kbase + 4);
  float4v xc = *(const float4v*)(xr + 32 + kbase);
  float4v xd = *(const float4v*)(xr + 32 + kbase + 4);
  short8 b0, b1;
#pragma unroll
  for (int i = 0; i < 4; ++i) {
    b0[i]     = (short)f2b(xa[i]);
    b0[i + 4] = (short)f2b(xb[i]);
    b1[i]     = (short)f2b(xc[i]);
    b1[i + 4] = (short)f2b(xd[i]);
  }

  const int ocb = (lane >> 4) * 4;
#pragma unroll
  for (int dd = 0; dd < 3; ++dd) {
    ushort* outQ = qbf + (size_t)dd * NP * CH;
    unsigned int* outKV = kvp + (size_t)dd * NP * CH;
#pragma unroll
    for (int mt = 0; mt < 4; ++mt) {       // ---- Q ----
      const ushort* qb = wpack + ((((size_t)dd * 4 + mt) * 2) * 64 + lane) * 8;
      short8 a0 = *(const short8*)(qb);
      short8 a1 = *(const short8*)(qb + 64 * 8);
      float4v acc = {0.f, 0.f, 0.f, 0.f};
      acc = __builtin_amdgcn_mfma_f32_16x16x32_bf16(a0, b0, acc, 0, 0, 0);
      acc = __builtin_amdgcn_mfma_f32_16x16x32_bf16(a1, b1, acc, 0, 0, 0);
      int oc = mt * 16 + ocb;
      uint2v o;
      o[0] = (unsigned)f2b(acc[0]) | ((unsigned)f2b(acc[1]) << 16);
      o[1] = (unsigned)f2b(acc[2]) | ((unsigned)f2b(acc[3]) << 16);
      *(uint2v*)(outQ + (size_t)myNode * CH + oc) = o;
    }
#pragma unroll
    for (int mt = 0; mt < 4; ++mt) {       // ---- K/V packed ----
      const ushort* kb = wpack +
          ((((size_t)(3 + dd) * 4 + mt) * 2) * 64 + lane) * 8;
      const ushort* vb = wpack +
          ((((size_t)(6 + dd) * 4 + mt) * 2) * 64 + lane) * 8;
      short8 k0 = *(const short8*)(kb);
      short8 k1 = *(const short8*)(kb + 64 * 8);
      short8 v0 = *(const short8*)(vb);
      short8 v1 = *(const short8*)(vb + 64 * 8);
      float4v aK = {0.f, 0.f, 0.f, 0.f};
      float4v aV = {0.f, 0.f, 0.f, 0.f};
      aK = __builtin_amdgcn_mfma_f32_16x16x32_bf16(k0, b0, aK, 0, 0, 0);
      aK = __builtin_amdgcn_mfma_f32_16x16x32_bf16(k1, b1, aK, 0, 0, 0);
      aV = __builtin_amdgcn_mfma_f32_16x16x32_bf16(v0, b0, aV, 0, 0, 0);
      aV = __builtin_amdgcn_mfma_f32_16x16x32_bf16(v1, b1, aV, 0, 0, 0);
      int oc = mt * 16 + ocb;
      uint4v o;
#pragma unroll
      for (int i = 0; i < 4; ++i)
        o[i] = ((unsigned)f2b(aK[i]) << 16) | (unsigned)f2b(aV[i]);
      *(uint4v*)(outKV + (size_t)myNode * CH + oc) = o;
    }
  }
}

// ---------------------------------------------------------------------------
// Kernel 2: fused attention. Block = (64,6): 4 nodes; wave wy = (dd, half),
// each handling 8 of a dilation's 16 edges.
// v2 changes vs previous round:
//   - stage only the 32 DISTINCT edges actually used by the dilation slices
//     (union of {0..15},{16,18..30},{32,36..60}) -> half the gather issue
//   - 8-deep explicit prefetch: all 8 KV loads issued while t[e] (the
//     load-independent q+delta work, 96 FMAs) computes -> covers L2 latency
//   - combine wave moved to wy=5, which PRELOADS pool partials + x residual
//     before the edge loop so the epilogue is pure LDS+VALU
// ---------------------------------------------------------------------------
__global__ __launch_bounds__(384, 4) void attn_kernel(
    const float* __restrict__ x,
    const float* __restrict__ pos,
    const float* __restrict__ Wp,
    const float* __restrict__ bp,
    const int*   __restrict__ edge_src,
    const ushort* __restrict__ qbf,
    const unsigned int* __restrict__ kvp,
    const float* __restrict__ poolP,
    float* __restrict__ out) {
  const int bx  = blockIdx.x;
  const int xcd = bx & 7;
  const int kk  = bx >> 3;
  const int base = (ATILES * xcd) >> 3;
  const int cnt  = ((ATILES * (xcd + 1)) >> 3) - base;
  if (kk >= cnt) return;                    // whole-block uniform
  const int node0 = (base + kk) * 4;

  const int wy   = threadIdx.y;             // 0..5
  const int dd   = wy % 3;                  // wave-uniform dilation
  const int half = wy / 3;                  // 0 or 1 (edge half)
  const int tid  = wy * 64 + threadIdx.x;

  __shared__ float sEdge[4 * 132];          // [nl][slot] {relx,rely,relz,rowOfs}
  __shared__ float sS[6 * 4 * 68];          // [wy][nl][ch] partial s
  __shared__ float sP[6 * 4 * 68];          // [wy][nl][ch] partial accv-q*s

  const int lane = threadIdx.x;
  const int g    = lane >> 4;
  const int cl   = lane & 15;
  const int node = node0 + g;

  // ---- epilogue preload (combine wave only): overlaps with everything ----
  float4v pvmax = {0.f, 0.f, 0.f, 0.f};
  float4v xres  = {0.f, 0.f, 0.f, 0.f};
  if (wy == 5) {
    const int b = node0 / PTS;              // 4-node tile never straddles cloud
    const float* pp = poolP + (size_t)(b * PPB) * CH + cl * 4;
    pvmax = *(const float4v*)pp;
#pragma unroll
    for (int q2 = 1; q2 < PPB; ++q2) {
      float4v t2 = *(const float4v*)(pp + (size_t)q2 * CH);
#pragma unroll
      for (int i = 0; i < 4; ++i) pvmax[i] = fmaxf(pvmax[i], t2[i]);
    }
    xres = *(const float4v*)(x + (size_t)node * CH + cl * 4);
  }

  // ---- stage: 4 nodes x 32 compacted edge slots (waves 0-1 only) ----
  if (tid < 128) {
    int nl   = tid >> 5;
    int slot = tid & 31;
    int p = slot < 16 ? slot : (slot < 24 ? slot * 2 - 16 : slot * 4 - 64);
    int nd = node0 + nl;
    int j = edge_src[(size_t)nd * KMAX + p];
    float4v w;
    w[0] = pos[nd * 3 + 0] - pos[j * 3 + 0];
    w[1] = pos[nd * 3 + 1] - pos[j * 3 + 1];
    w[2] = pos[nd * 3 + 2] - pos[j * 3 + 2];
    w[3] = __int_as_float(j << 8);          // byte offset of packed-KV row
    *(float4v*)&sEdge[nl * 132 + slot * 4] = w;
  }

  const unsigned clOfs = (unsigned)(cl << 4);

  float4v bq, qorig, wp0, wp1, wp2;
  {
    ushort4v qh = *(const ushort4v*)(qbf + ((size_t)dd * NP + node) * CH + cl * 4);
    const float* WpD = Wp + dd * 192;
    wp0 = *(const float4v*)(WpD + 0 * 64 + cl * 4) * L2E;
    wp1 = *(const float4v*)(WpD + 1 * 64 + cl * 4) * L2E;
    wp2 = *(const float4v*)(WpD + 2 * 64 + cl * 4) * L2E;
    float4v bpv = *(const float4v*)(bp + dd * 64 + cl * 4);
    float4v qf;
#pragma unroll
    for (int i = 0; i < 4; ++i) qf[i] = b2f(qh[i]);
    bq = qf + bpv * L2E;
    qorig = qf * LN2;
  }
  const char* KVb = (const char*)(kvp + (size_t)dd * NP * CH);
  const unsigned long long slotq = SLOTQ[wy];

  __syncthreads();

  // ---- phase 1: read w, issue ALL 8 KV gathers, compute t[e] under them ----
  const float* eb = &sEdge[g * 132];
  float4v t[8];
  uint4v  u[8];
#pragma unroll
  for (int e = 0; e < 8; ++e) {
    int so = (int)((slotq >> (8 * e)) & 0xFF) * 4;
    float4v w = *(const float4v*)(eb + so);
    u[e] = *(const uint4v*)(KVb + (__float_as_uint(w[3]) + clOfs));
    t[e] = bq + w[0] * wp0 + w[1] * wp1 + w[2] * wp2;   // q_s + delta_s
  }

  // ---- phase 2: consume in issue order ----
  float4v s    = {0.f, 0.f, 0.f, 0.f};
  float4v accv = {0.f, 0.f, 0.f, 0.f};
#pragma unroll
  for (int e = 0; e < 8; ++e) {
    uint4v uu = u[e];
    float4v kf, vf, wgt;
#pragma unroll
    for (int i = 0; i < 4; ++i) kf[i] = __uint_as_float(uu[i] & 0xFFFF0000u);
#pragma unroll
    for (int i = 0; i < 4; ++i) vf[i] = __uint_as_float(uu[i] << 16);
    float4v a = t[e] - kf;
#pragma unroll
    for (int i = 0; i < 4; ++i) wgt[i] = __builtin_amdgcn_exp2f(a[i]);
    s += wgt;
    accv += wgt * (vf + t[e] * LN2);        // w * (v + ln2*t)
  }

  // publish partials: P = accv - q*s  (q uniform across halves)
  float4v P = accv - qorig * s;
  *(float4v*)&sS[(wy * 4 + g) * 68 + cl * 4] = s;
  *(float4v*)&sP[(wy * 4 + g) * 68 + cl * 4] = P;
  __syncthreads();

  if (wy == 5) {                            // combine wave (preloaded pool/x)
    float4v res;
#pragma unroll
    for (int d2 = 0; d2 < 3; ++d2) {
      float4v s0 = *(const float4v*)&sS[((d2    ) * 4 + g) * 68 + cl * 4];
      float4v s1 = *(const float4v*)&sS[((d2 + 3) * 4 + g) * 68 + cl * 4];
      float4v p0 = *(const float4v*)&sP[((d2    ) * 4 + g) * 68 + cl * 4];
      float4v p1 = *(const float4v*)&sP[((d2 + 3) * 4 + g) * 68 + cl * 4];
      float4v st = s0 + s1;
      float4v pt = p0 + p1;
      float4v r;
#pragma unroll
      for (int i = 0; i < 4; ++i)
        r[i] = pt[i] * __builtin_amdgcn_rcpf(st[i] + EPSF);
      if (d2 == 0) res = r;
      else {
#pragma unroll
        for (int i = 0; i < 4; ++i) res[i] = fmaxf(res[i], r[i]);
      }
    }
#pragma unroll
    for (int i = 0; i < 4; ++i) res[i] = fmaxf(res[i], pvmax[i]) + xres[i];
    *(float4v*)(out + (size_t)node * CH + cl * 4) = res;
  }
}

// ---------------------------------------------------------------------------
extern "C" void kernel_launch(void* const* d_in, const int* in_sizes, int n_in,
                              void* d_out, int out_size, void* d_ws, size_t ws_size,
                              hipStream_t stream) {
  const float* x    = (const float*)d_in[0];
  const float* pos  = (const float*)d_in[1];
  const float* Wv   = (const float*)d_in[2];
  const float* Wq   = (const float*)d_in[3];
  const float* Wk   = (const float*)d_in[4];
  const float* Wp   = (const float*)d_in[5];
  const float* bp   = (const float*)d_in[6];
  const int*   ei   = (const int*)d_in[7];
  float* out = (float*)d_out;

  char* wsb = (char*)d_ws;
  ushort* qbf   = (ushort*)wsb;
  unsigned int* kvp = (unsigned int*)(wsb + QBF_BYTES);
  ushort* wpack = (ushort*)(wsb + QBF_BYTES + KVP_BYTES);
  float*  poolP = (float*)(wsb + QBF_BYTES + KVP_BYTES +
                           (size_t)WPACK_ELEMS * 2);

  // 0) pool partials + W pack
  {
    int packBlocks = (WPACK_ELEMS + 255) / 256;
    dim3 grid(NB * PPB + packBlocks);
    hipLaunchKernelGGL(prep_kernel, grid, dim3(256), 0, stream,
                       x, Wv, Wq, Wk, wpack, poolP);
  }
  // 1) Q + packed KV via MFMA (single pass, 72 MFMA/wave, x read once)
  {
    dim3 grid((NTILES + 3) / 4);
    dim3 block(64, 4);
    hipLaunchKernelGGL(qkv_mfma, grid, block, 0, stream, x, wpack, qbf, kvp);
  }
  // 2) fused attention + combine
  {
    dim3 grid(8 * ((ATILES + 7) / 8));
    dim3 block(64, 6);
    hipLaunchKernelGGL(attn_kernel, grid, block, 0, stream,
                       x, pos, Wp, bp, ei, qbf, kvp, poolP, out);
  }
}

// Round 2
// 203.764 us; speedup vs baseline: 1.0133x; 1.0133x over previous
//
#include <hip/hip_runtime.h>
#include <math.h>

#define NP 50000
#define CH 64
#define KMAX 64
#define KNN 16
#define NB 25
#define PTS (NP / NB)            // 2000
#define EPSF 1e-16f
#define NTILES (NP / 16)         // 3125 (16-node tiles for qkv)
#define ATILES8 (NP / 8)         // 6250 (8-node tiles for attn)
#define L2E 1.4426950408889634f
#define LN2 0.6931471805599453f
#define PPB 8                    // pool partials per cloud
#define PROWS (PTS / PPB)        // 250

typedef __attribute__((ext_vector_type(8))) short short8;
typedef __attribute__((ext_vector_type(4))) float float4v;
typedef __attribute__((ext_vector_type(4))) unsigned int uint4v;
typedef __attribute__((ext_vector_type(2))) unsigned int uint2v;
typedef __attribute__((ext_vector_type(4))) unsigned short ushort4v;

__device__ __forceinline__ ushort f2b(float f) {
  unsigned u = __float_as_uint(f);
  unsigned r = (u + 0x7FFFu + ((u >> 16) & 1u)) >> 16;
  return (ushort)r;
}
__device__ __forceinline__ float b2f(ushort h) {
  return __uint_as_float(((unsigned)h) << 16);
}

// ws layout (bytes):
//   qbf  : 3 * NP * CH * 2   (bf16, log2e-scaled Q)
//   kvp  : 3 * NP * CH * 4   (packed dword: K_s bf16 hi | V bf16 lo)
//   x_bf : NP * CH * 2
//   wpack: 36864 ushort (A-frag layout; Q,K pre-scaled by log2e)
//   poolP: NB * PPB * CH fp32 (per-cloud pool partials)
#define QBF_BYTES   ((size_t)3 * NP * CH * 2)
#define KVP_BYTES   ((size_t)3 * NP * CH * 4)
#define XBF_BYTES   ((size_t)NP * CH * 2)
#define WPACK_ELEMS (9 * 4 * 2 * 64 * 8)
#define XV (NP * CH / 4)

// ---------------------------------------------------------------------------
// Kernel 0: prep = pool partials (blocks 0..NB*PPB-1) + x->bf16 + W pack.
// (round-0 proven version)
// ---------------------------------------------------------------------------
__global__ __launch_bounds__(256) void prep_kernel(
    const float* __restrict__ x,
    const float* __restrict__ Wv,
    const float* __restrict__ Wq,
    const float* __restrict__ Wk,
    ushort* __restrict__ x_bf,
    ushort* __restrict__ wpack,
    float* __restrict__ poolP) {
  const int tid = threadIdx.x;
  const int bid = blockIdx.x;
  __shared__ float red[4][CH];

  if (bid < NB * PPB) {                 // ---- pool partial path ----
    const int lane = tid & 63;
    const int wave = tid >> 6;
    const int cloud = bid >> 3;
    const int part  = bid & 7;
    const float* xb = x + ((size_t)cloud * PTS + part * PROWS) * CH;
    float m0 = -INFINITY, m1 = -INFINITY;
    for (int r = wave * 2; r < PROWS; r += 8) {
      m0 = fmaxf(m0, xb[(size_t)(r + 0) * CH + lane]);
      m1 = fmaxf(m1, xb[(size_t)(r + 1) * CH + lane]);
    }
    red[wave][lane] = fmaxf(m0, m1);
    __syncthreads();
    if (wave == 0) {
      poolP[(size_t)bid * CH + lane] = fmaxf(fmaxf(red[0][lane], red[1][lane]),
                                             fmaxf(red[2][lane], red[3][lane]));
    }
  } else {                              // ---- convert / pack path ----
    const int gid = (bid - NB * PPB) * 256 + tid;
    if (gid < XV) {
      const float4* xv = (const float4*)x;
      float4 v = xv[gid];
      ushort4v o;
      o[0] = f2b(v.x); o[1] = f2b(v.y); o[2] = f2b(v.z); o[3] = f2b(v.w);
      *(ushort4v*)(x_bf + (size_t)gid * 4) = o;
    } else {
      int pid = gid - XV;
      if (pid < WPACK_ELEMS) {
        int j     = pid & 7;
        int lane  = (pid >> 3) & 63;
        int kstep = (pid >> 9) & 1;
        int mtile = (pid >> 10) & 3;
        int mat   = pid >> 12;
        const float* W;
        int d;
        float scale;
        if (mat < 3)      { W = Wq; d = mat;     scale = L2E; }
        else if (mat < 6) { W = Wk; d = mat - 3; scale = L2E; }
        else              { W = Wv; d = mat - 6; scale = 1.f; }
        int oc = mtile * 16 + (lane & 15);
        int ic = kstep * 32 + ((lane >> 4) & 3) * 8 + j;
        wpack[pid] = f2b(W[d * CH * CH + ic * CH + oc] * scale);
      }
    }
  }
}

// ---------------------------------------------------------------------------
// Kernel 1: projections via MFMA 16x16x32 bf16 (A=W^T, B=x^T). 1 tile/wave.
// grid.y: 0..2 = Q_dd (8 A-frags), 3..5 = KV_dd packed (16 A-frags).
// (round-0 proven version)
// ---------------------------------------------------------------------------
__global__ __launch_bounds__(256) void qkv_mfma(
    const ushort* __restrict__ x_bf,
    const ushort* __restrict__ wpack,
    ushort* __restrict__ qbf,
    unsigned int* __restrict__ kvp) {
  const int lane = threadIdx.x;
  const int tile = blockIdx.x * 4 + threadIdx.y;
  if (tile >= NTILES) return;
  const int y = blockIdx.y;
  const int kbase = (lane >> 4) * 8;
  const int myNode = tile * 16 + (lane & 15);
  const ushort* xr = x_bf + (size_t)myNode * CH;
  short8 b0 = *(const short8*)(xr + kbase);
  short8 b1 = *(const short8*)(xr + 32 + kbase);

  if (y < 3) {                             // ---- Q slice ----
    const int dd = y;
    ushort* outQ = qbf + (size_t)dd * NP * CH;
#pragma unroll
    for (int mt = 0; mt < 4; ++mt) {
      short8 a0 = *(const short8*)(wpack +
          ((((size_t)dd * 4 + mt) * 2 + 0) * 64 + lane) * 8);
      short8 a1 = *(const short8*)(wpack +
          ((((size_t)dd * 4 + mt) * 2 + 1) * 64 + lane) * 8);
      float4v acc = {0.f, 0.f, 0.f, 0.f};
      acc = __builtin_amdgcn_mfma_f32_16x16x32_bf16(a0, b0, acc, 0, 0, 0);
      acc = __builtin_amdgcn_mfma_f32_16x16x32_bf16(a1, b1, acc, 0, 0, 0);
      int oc = mt * 16 + (lane >> 4) * 4;
      uint2v o;
      o[0] = (unsigned)f2b(acc[0]) | ((unsigned)f2b(acc[1]) << 16);
      o[1] = (unsigned)f2b(acc[2]) | ((unsigned)f2b(acc[3]) << 16);
      *(uint2v*)(outQ + (size_t)myNode * CH + oc) = o;
    }
  } else {                                 // ---- KV packed slice ----
    const int dd = y - 3;
    unsigned int* outKV = kvp + (size_t)dd * NP * CH;
#pragma unroll
    for (int mt = 0; mt < 4; ++mt) {
      short8 k0 = *(const short8*)(wpack +
          ((((size_t)(3 + dd) * 4 + mt) * 2 + 0) * 64 + lane) * 8);
      short8 k1 = *(const short8*)(wpack +
          ((((size_t)(3 + dd) * 4 + mt) * 2 + 1) * 64 + lane) * 8);
      short8 v0 = *(const short8*)(wpack +
          ((((size_t)(6 + dd) * 4 + mt) * 2 + 0) * 64 + lane) * 8);
      short8 v1 = *(const short8*)(wpack +
          ((((size_t)(6 + dd) * 4 + mt) * 2 + 1) * 64 + lane) * 8);
      float4v aK = {0.f, 0.f, 0.f, 0.f};
      float4v aV = {0.f, 0.f, 0.f, 0.f};
      aK = __builtin_amdgcn_mfma_f32_16x16x32_bf16(k0, b0, aK, 0, 0, 0);
      aK = __builtin_amdgcn_mfma_f32_16x16x32_bf16(k1, b1, aK, 0, 0, 0);
      aV = __builtin_amdgcn_mfma_f32_16x16x32_bf16(v0, b0, aV, 0, 0, 0);
      aV = __builtin_amdgcn_mfma_f32_16x16x32_bf16(v1, b1, aV, 0, 0, 0);
      int oc = mt * 16 + (lane >> 4) * 4;
      uint4v o;
#pragma unroll
      for (int i = 0; i < 4; ++i)
        o[i] = ((unsigned)f2b(aK[i]) << 16) | (unsigned)f2b(aV[i]);
      *(uint4v*)(outKV + (size_t)myNode * CH + oc) = o;
    }
  }
}

// ---------------------------------------------------------------------------
// Kernel 2: fused attention, v3. Block = (64,6) but now 8 NODES per block
// (6250 blocks instead of 12500): two sequential 4-node passes reusing the
// dd-dependent setup (wp0-2, bp, KV base). Inner 8-edge loop is the proven
// round-0 interleaved body, untouched (the v2 explicit prefetch regressed).
// Edge staging: 48 per-wave-CONTIGUOUS slots per node (exactly 384 = one
// slot/thread; 25% fewer gathers than 64); each wave walks its 8 slots at
// uniform stride 16B (broadcast within 16-lane group, stride-784B across
// groups -> conflict-free). Combine wave = wy 5, pool/x preloaded upfront.
// ---------------------------------------------------------------------------
__global__ __launch_bounds__(384, 6) void attn_kernel(
    const float* __restrict__ x,
    const float* __restrict__ pos,
    const float* __restrict__ Wp,
    const float* __restrict__ bp,
    const int*   __restrict__ edge_src,
    const ushort* __restrict__ qbf,
    const unsigned int* __restrict__ kvp,
    const float* __restrict__ poolP,
    float* __restrict__ out) {
  const int bx  = blockIdx.x;
  const int xcd = bx & 7;
  const int kk  = bx >> 3;
  const int base = (ATILES8 * xcd) >> 3;
  const int cnt  = ((ATILES8 * (xcd + 1)) >> 3) - base;
  if (kk >= cnt) return;                    // whole-block uniform
  const int node0 = (base + kk) * 8;

  const int wy   = threadIdx.y;             // 0..5
  const int dd   = wy % 3;                  // wave-uniform dilation
  const int tid  = wy * 64 + threadIdx.x;
  const int lane = threadIdx.x;
  const int g    = lane >> 4;
  const int cl   = lane & 15;

  __shared__ float sEdge[8 * 196];          // [nl][slot*4] {relx,rely,relz,rowOfs}
  __shared__ float sS[6 * 8 * 68];          // [wy][nl][ch] partial s
  __shared__ float sP[6 * 8 * 68];          // [wy][nl][ch] partial accv-q*s

  // ---- epilogue preload (combine wave only): overlaps with everything ----
  float4v pvmax = {0.f, 0.f, 0.f, 0.f};
  float4v xresA = {0.f, 0.f, 0.f, 0.f};
  float4v xresB = {0.f, 0.f, 0.f, 0.f};
  if (wy == 5) {
    const int b = node0 / PTS;              // 8-node tile never straddles cloud
    const float* pp = poolP + (size_t)(b * PPB) * CH + cl * 4;
    pvmax = *(const float4v*)pp;
#pragma unroll
    for (int q2 = 1; q2 < PPB; ++q2) {
      float4v t2 = *(const float4v*)(pp + (size_t)q2 * CH);
#pragma unroll
      for (int i = 0; i < 4; ++i) pvmax[i] = fmaxf(pvmax[i], t2[i]);
    }
    xresA = *(const float4v*)(x + (size_t)(node0 + g) * CH + cl * 4);
    xresB = *(const float4v*)(x + (size_t)(node0 + 4 + g) * CH + cl * 4);
  }

  // ---- stage: 8 nodes x 48 slots, one per thread ----
  // slot s -> wave wv=s>>3, e=s&7, dil dds=wv%3; edge p = (wv>=3?8<<dds:0)+(e<<dds)
  {
    int nl = tid / 48;                      // 0..7
    int s  = tid - nl * 48;                 // 0..47
    int wv = s >> 3, e = s & 7;
    int dds = wv >= 3 ? wv - 3 : wv;
    int p = (wv >= 3 ? (8 << dds) : 0) + (e << dds);
    int nd = node0 + nl;
    int j = edge_src[(size_t)nd * KMAX + p];
    float4v w;
    w[0] = pos[nd * 3 + 0] - pos[j * 3 + 0];
    w[1] = pos[nd * 3 + 1] - pos[j * 3 + 1];
    w[2] = pos[nd * 3 + 2] - pos[j * 3 + 2];
    w[3] = __int_as_float(j << 8);          // byte offset of packed-KV row
    *(float4v*)&sEdge[nl * 196 + s * 4] = w;
  }

  // ---- dd-dependent setup, shared across both passes ----
  const unsigned clOfs = (unsigned)(cl << 4);
  float4v wp0, wp1, wp2, bqadd;
  {
    const float* WpD = Wp + dd * 192;
    wp0 = *(const float4v*)(WpD + 0 * 64 + cl * 4) * L2E;
    wp1 = *(const float4v*)(WpD + 1 * 64 + cl * 4) * L2E;
    wp2 = *(const float4v*)(WpD + 2 * 64 + cl * 4) * L2E;
    bqadd = *(const float4v*)(bp + dd * 64 + cl * 4) * L2E;
  }
  const char* KVb = (const char*)(kvp + (size_t)dd * NP * CH);

  __syncthreads();

  // ---- two 4-node passes, proven round-0 inner body ----
  for (int p2 = 0; p2 < 2; ++p2) {
    const int node = node0 + p2 * 4 + g;
    ushort4v qh = *(const ushort4v*)(qbf + ((size_t)dd * NP + node) * CH + cl * 4);
    float4v qf;
#pragma unroll
    for (int i = 0; i < 4; ++i) qf[i] = b2f(qh[i]);
    float4v bq = qf + bqadd;
    float4v qorig = qf * LN2;

    const float* eb = &sEdge[(p2 * 4 + g) * 196 + wy * 32];
    float4v sAcc = {0.f, 0.f, 0.f, 0.f};
    float4v accv = {0.f, 0.f, 0.f, 0.f};
#pragma unroll
    for (int e = 0; e < 8; ++e) {
      float4v w = *(const float4v*)(eb + e * 4);
      uint4v u = *(const uint4v*)(KVb + (__float_as_uint(w[3]) + clOfs));
      float4v kf, vf, wgt;
#pragma unroll
      for (int i = 0; i < 4; ++i) kf[i] = __uint_as_float(u[i] & 0xFFFF0000u);
#pragma unroll
      for (int i = 0; i < 4; ++i) vf[i] = __uint_as_float(u[i] << 16);
      float4v t = bq + w[0] * wp0 + w[1] * wp1 + w[2] * wp2;  // q_s + delta_s
      float4v a = t - kf;
#pragma unroll
      for (int i = 0; i < 4; ++i) wgt[i] = __builtin_amdgcn_exp2f(a[i]);
      sAcc += wgt;
      accv += wgt * (vf + t * LN2);         // w * (v + ln2*t)
    }

    // publish partials: P = accv - q*s  (q uniform across halves)
    float4v P = accv - qorig * sAcc;
    *(float4v*)&sS[(wy * 8 + p2 * 4 + g) * 68 + cl * 4] = sAcc;
    *(float4v*)&sP[(wy * 8 + p2 * 4 + g) * 68 + cl * 4] = P;
  }
  __syncthreads();

  if (wy == 5) {                            // combine wave (preloaded pool/x)
#pragma unroll
    for (int p2 = 0; p2 < 2; ++p2) {
      float4v res;
#pragma unroll
      for (int d2 = 0; d2 < 3; ++d2) {
        float4v s0 = *(const float4v*)&sS[((d2    ) * 8 + p2 * 4 + g) * 68 + cl * 4];
        float4v s1 = *(const float4v*)&sS[((d2 + 3) * 8 + p2 * 4 + g) * 68 + cl * 4];
        float4v p0 = *(const float4v*)&sP[((d2    ) * 8 + p2 * 4 + g) * 68 + cl * 4];
        float4v p1 = *(const float4v*)&sP[((d2 + 3) * 8 + p2 * 4 + g) * 68 + cl * 4];
        float4v st = s0 + s1;
        float4v pt = p0 + p1;
        float4v r;
#pragma unroll
        for (int i = 0; i < 4; ++i)
          r[i] = pt[i] * __builtin_amdgcn_rcpf(st[i] + EPSF);
        if (d2 == 0) res = r;
        else {
#pragma unroll
          for (int i = 0; i < 4; ++i) res[i] = fmaxf(res[i], r[i]);
        }
      }
      float4v xres = p2 ? xresB : xresA;
#pragma unroll
      for (int i = 0; i < 4; ++i) res[i] = fmaxf(res[i], pvmax[i]) + xres[i];
      *(float4v*)(out + (size_t)(node0 + p2 * 4 + g) * CH + cl * 4) = res;
    }
  }
}

// ---------------------------------------------------------------------------
extern "C" void kernel_launch(void* const* d_in, const int* in_sizes, int n_in,
                              void* d_out, int out_size, void* d_ws, size_t ws_size,
                              hipStream_t stream) {
  const float* x    = (const float*)d_in[0];
  const float* pos  = (const float*)d_in[1];
  const float* Wv   = (const float*)d_in[2];
  const float* Wq   = (const float*)d_in[3];
  const float* Wk   = (const float*)d_in[4];
  const float* Wp   = (const float*)d_in[5];
  const float* bp   = (const float*)d_in[6];
  const int*   ei   = (const int*)d_in[7];
  float* out = (float*)d_out;

  char* wsb = (char*)d_ws;
  ushort* qbf   = (ushort*)wsb;
  unsigned int* kvp = (unsigned int*)(wsb + QBF_BYTES);
  ushort* x_bf  = (ushort*)(wsb + QBF_BYTES + KVP_BYTES);
  ushort* wpack = (ushort*)(wsb + QBF_BYTES + KVP_BYTES + XBF_BYTES);
  float*  poolP = (float*)(wsb + QBF_BYTES + KVP_BYTES + XBF_BYTES +
                           (size_t)WPACK_ELEMS * 2);

  // 0) pool partials + convert + pack
  {
    int convBlocks = (XV + WPACK_ELEMS + 255) / 256;
    dim3 grid(NB * PPB + convBlocks);
    hipLaunchKernelGGL(prep_kernel, grid, dim3(256), 0, stream,
                       x, Wv, Wq, Wk, x_bf, wpack, poolP);
  }
  // 1) Q + packed KV via MFMA (6 slices, 1 tile/wave)
  {
    dim3 grid((NTILES + 3) / 4, 6);
    dim3 block(64, 4);
    hipLaunchKernelGGL(qkv_mfma, grid, block, 0, stream, x_bf, wpack, qbf, kvp);
  }
  // 2) fused attention + combine (8 nodes/block)
  {
    dim3 grid(8 * ((ATILES8 + 7) / 8));
    dim3 block(64, 6);
    hipLaunchKernelGGL(attn_kernel, grid, block, 0, stream,
                       x, pos, Wp, bp, ei, qbf, kvp, poolP, out);
  }
}

// Round 3
// 191.072 us; speedup vs baseline: 1.0806x; 1.0664x over previous
//
#include <hip/hip_runtime.h>
#include <math.h>

#define NP 50000
#define CH 64
#define KMAX 64
#define KNN 16
#define NB 25
#define PTS (NP / NB)            // 2000
#define EPSF 1e-16f
#define NTILES (NP / 16)         // 3125 (16-node tiles for qkv)
#define ATILES (NP / 4)          // 12500 (4-node tiles for attn)
#define L2E 1.4426950408889634f
#define LN2 0.6931471805599453f
#define PPB 8                    // pool partials per cloud
#define PROWS (PTS / PPB)        // 250

typedef __attribute__((ext_vector_type(8))) short short8;
typedef __attribute__((ext_vector_type(4))) float float4v;
typedef __attribute__((ext_vector_type(4))) unsigned int uint4v;
typedef __attribute__((ext_vector_type(2))) unsigned int uint2v;
typedef __attribute__((ext_vector_type(4))) unsigned short ushort4v;

__device__ __forceinline__ ushort f2b(float f) {
  unsigned u = __float_as_uint(f);
  unsigned r = (u + 0x7FFFu + ((u >> 16) & 1u)) >> 16;
  return (ushort)r;
}
__device__ __forceinline__ float b2f(ushort h) {
  return __uint_as_float(((unsigned)h) << 16);
}

// ws layout (bytes):
//   qbf  : 3 * NP * CH * 2   (bf16, log2e-scaled Q)
//   kvp  : 3 * NP * CH * 4   (packed dword: K_s bf16 hi | V bf16 lo)
//   wpack: 36864 ushort (A-frag layout; Q,K pre-scaled by log2e)
//   poolP: NB * PPB * CH fp32 (per-cloud pool partials)
#define QBF_BYTES   ((size_t)3 * NP * CH * 2)
#define KVP_BYTES   ((size_t)3 * NP * CH * 4)
#define WPACK_ELEMS (9 * 4 * 2 * 64 * 8)

// ---------------------------------------------------------------------------
// Kernel 0: prep = pool partials (blocks 0..NB*PPB-1) + W pack.
// (x->bf16 conversion now lives inside qkv_mfma's LDS staging.)
// ---------------------------------------------------------------------------
__global__ __launch_bounds__(256) void prep_kernel(
    const float* __restrict__ x,
    const float* __restrict__ Wv,
    const float* __restrict__ Wq,
    const float* __restrict__ Wk,
    ushort* __restrict__ wpack,
    float* __restrict__ poolP) {
  const int tid = threadIdx.x;
  const int bid = blockIdx.x;
  __shared__ float red[4][CH];

  if (bid < NB * PPB) {                 // ---- pool partial path ----
    const int lane = tid & 63;
    const int wave = tid >> 6;
    const int cloud = bid >> 3;
    const int part  = bid & 7;
    const float* xb = x + ((size_t)cloud * PTS + part * PROWS) * CH;
    float m0 = -INFINITY, m1 = -INFINITY;
    for (int r = wave * 2; r < PROWS; r += 8) {
      m0 = fmaxf(m0, xb[(size_t)(r + 0) * CH + lane]);
      m1 = fmaxf(m1, xb[(size_t)(r + 1) * CH + lane]);
    }
    red[wave][lane] = fmaxf(m0, m1);
    __syncthreads();
    if (wave == 0) {
      poolP[(size_t)bid * CH + lane] = fmaxf(fmaxf(red[0][lane], red[1][lane]),
                                             fmaxf(red[2][lane], red[3][lane]));
    }
  } else {                              // ---- W pack path ----
    int pid = (bid - NB * PPB) * 256 + tid;
    if (pid < WPACK_ELEMS) {
      int j     = pid & 7;
      int lane  = (pid >> 3) & 63;
      int kstep = (pid >> 9) & 1;
      int mtile = (pid >> 10) & 3;
      int mat   = pid >> 12;
      const float* W;
      int d;
      float scale;
      if (mat < 3)      { W = Wq; d = mat;     scale = L2E; }
      else if (mat < 6) { W = Wk; d = mat - 3; scale = L2E; }
      else              { W = Wv; d = mat - 6; scale = 1.f; }
      int oc = mtile * 16 + (lane & 15);
      int ic = kstep * 32 + ((lane >> 4) & 3) * 8 + j;
      wpack[pid] = f2b(W[d * CH * CH + ic * CH + oc] * scale);
    }
  }
}

// ---------------------------------------------------------------------------
// Kernel 1: projections via MFMA 16x16x32 bf16. One block per 16-node tile,
// 6 waves = 6 slices (wy 0..2 = Q_dd, wy 3..5 = KV_dd packed). The tile's x
// rows are staged ONCE from f32 global into 2 KB of XOR-swizzled LDS
// (x read 12.8 MB total instead of 38.4 MB bf16 re-reads; x_bf eliminated).
// Swizzle: byte ^= (node&7)<<4 within each 128B row -> ds_read_b128 2-way.
// ---------------------------------------------------------------------------
__global__ __launch_bounds__(384) void qkv_mfma(
    const float* __restrict__ x,
    const ushort* __restrict__ wpack,
    ushort* __restrict__ qbf,
    unsigned int* __restrict__ kvp) {
  const int tile = blockIdx.x;
  const int lane = threadIdx.x;
  const int wy   = threadIdx.y;
  const int tid  = wy * 64 + lane;

  __shared__ ushort xs[16 * 64];            // 2 KB, XOR-swizzled rows

  if (tid < 256) {                          // stage: 16 nodes x 16 chunks(4ch)
    int node  = tid >> 4;
    int chunk = tid & 15;
    float4v v = *(const float4v*)(x + ((size_t)(tile * 16 + node)) * CH + chunk * 4);
    ushort4v o;
    o[0] = f2b(v[0]); o[1] = f2b(v[1]); o[2] = f2b(v[2]); o[3] = f2b(v[3]);
    int byte = (chunk * 8) ^ ((node & 7) << 4);
    *(ushort4v*)((char*)xs + node * 128 + byte) = o;
  }
  __syncthreads();

  const int node = lane & 15;
  const int kb2  = (lane >> 4) * 16;        // byte offset of this group's k-slice
  const char* xrow = (const char*)xs + node * 128;
  const int sw = (node & 7) << 4;
  short8 b0 = *(const short8*)(xrow + (kb2 ^ sw));
  short8 b1 = *(const short8*)(xrow + ((kb2 + 64) ^ sw));
  const int myNode = tile * 16 + node;

  if (wy < 3) {                             // ---- Q slice ----
    const int dd = wy;
    ushort* outQ = qbf + (size_t)dd * NP * CH;
#pragma unroll
    for (int mt = 0; mt < 4; ++mt) {
      short8 a0 = *(const short8*)(wpack +
          ((((size_t)dd * 4 + mt) * 2 + 0) * 64 + lane) * 8);
      short8 a1 = *(const short8*)(wpack +
          ((((size_t)dd * 4 + mt) * 2 + 1) * 64 + lane) * 8);
      float4v acc = {0.f, 0.f, 0.f, 0.f};
      acc = __builtin_amdgcn_mfma_f32_16x16x32_bf16(a0, b0, acc, 0, 0, 0);
      acc = __builtin_amdgcn_mfma_f32_16x16x32_bf16(a1, b1, acc, 0, 0, 0);
      int oc = mt * 16 + (lane >> 4) * 4;
      uint2v o;
      o[0] = (unsigned)f2b(acc[0]) | ((unsigned)f2b(acc[1]) << 16);
      o[1] = (unsigned)f2b(acc[2]) | ((unsigned)f2b(acc[3]) << 16);
      *(uint2v*)(outQ + (size_t)myNode * CH + oc) = o;
    }
  } else {                                  // ---- KV packed slice ----
    const int dd = wy - 3;
    unsigned int* outKV = kvp + (size_t)dd * NP * CH;
#pragma unroll
    for (int mt = 0; mt < 4; ++mt) {
      short8 k0 = *(const short8*)(wpack +
          ((((size_t)(3 + dd) * 4 + mt) * 2 + 0) * 64 + lane) * 8);
      short8 k1 = *(const short8*)(wpack +
          ((((size_t)(3 + dd) * 4 + mt) * 2 + 1) * 64 + lane) * 8);
      short8 v0 = *(const short8*)(wpack +
          ((((size_t)(6 + dd) * 4 + mt) * 2 + 0) * 64 + lane) * 8);
      short8 v1 = *(const short8*)(wpack +
          ((((size_t)(6 + dd) * 4 + mt) * 2 + 1) * 64 + lane) * 8);
      float4v aK = {0.f, 0.f, 0.f, 0.f};
      float4v aV = {0.f, 0.f, 0.f, 0.f};
      aK = __builtin_amdgcn_mfma_f32_16x16x32_bf16(k0, b0, aK, 0, 0, 0);
      aK = __builtin_amdgcn_mfma_f32_16x16x32_bf16(k1, b1, aK, 0, 0, 0);
      aV = __builtin_amdgcn_mfma_f32_16x16x32_bf16(v0, b0, aV, 0, 0, 0);
      aV = __builtin_amdgcn_mfma_f32_16x16x32_bf16(v1, b1, aV, 0, 0, 0);
      int oc = mt * 16 + (lane >> 4) * 4;
      uint4v o;
#pragma unroll
      for (int i = 0; i < 4; ++i)
        o[i] = ((unsigned)f2b(aK[i]) << 16) | (unsigned)f2b(aV[i]);
      *(uint4v*)(outKV + (size_t)myNode * CH + oc) = o;
    }
  }
}

// ---------------------------------------------------------------------------
// Kernel 2: fused attention — EXACT round-0 proven version (79.9 us).
// Block = (64,6): 4 nodes; wave wy = (dd, half), each handling 8 of a
// dilation's 16 edges. Partials published as {s, P = accv - q*s} -> single
// combine wave, only TWO barriers total. XCD swizzle keeps each XCD's
// gathers in ~3 clouds (L2-resident KV).
// ---------------------------------------------------------------------------
__global__ __launch_bounds__(384, 6) void attn_kernel(
    const float* __restrict__ x,
    const float* __restrict__ pos,
    const float* __restrict__ Wp,
    const float* __restrict__ bp,
    const int*   __restrict__ edge_src,
    const ushort* __restrict__ qbf,
    const unsigned int* __restrict__ kvp,
    const float* __restrict__ poolP,
    float* __restrict__ out) {
  const int bx  = blockIdx.x;
  const int xcd = bx & 7;
  const int kk  = bx >> 3;
  const int base = (ATILES * xcd) >> 3;
  const int cnt  = ((ATILES * (xcd + 1)) >> 3) - base;
  if (kk >= cnt) return;                    // whole-block uniform
  const int node0 = (base + kk) * 4;

  const int wy   = threadIdx.y;             // 0..5
  const int dd   = wy % 3;                  // wave-uniform dilation
  const int half = wy / 3;                  // 0 or 1 (edge half)
  const int tid  = wy * 64 + threadIdx.x;

  __shared__ float sEdge[4 * 260];          // [nl][p] {relx,rely,relz,rowOfs}
  __shared__ float sS[6 * 4 * 68];          // [wy][nl][ch] partial s
  __shared__ float sP[6 * 4 * 68];          // [wy][nl][ch] partial accv-q*s

  if (tid < 256) {
    int nl = tid >> 6, p = tid & 63;
    int nd = node0 + nl;
    int j = edge_src[(size_t)nd * KMAX + p];
    float4v w;
    w[0] = pos[nd * 3 + 0] - pos[j * 3 + 0];
    w[1] = pos[nd * 3 + 1] - pos[j * 3 + 1];
    w[2] = pos[nd * 3 + 2] - pos[j * 3 + 2];
    w[3] = __int_as_float(j << 8);          // byte offset of packed-KV row
    *(float4v*)&sEdge[nl * 260 + p * 4] = w;
  }
  __syncthreads();

  const int lane = threadIdx.x;
  const int g    = lane >> 4;
  const int cl   = lane & 15;
  const int node = node0 + g;
  const unsigned clOfs = (unsigned)(cl << 4);

  float4v bq, qorig, wp0, wp1, wp2;
  {
    ushort4v qh = *(const ushort4v*)(qbf + ((size_t)dd * NP + node) * CH + cl * 4);
    const float* WpD = Wp + dd * 192;
    wp0 = *(const float4v*)(WpD + 0 * 64 + cl * 4) * L2E;
    wp1 = *(const float4v*)(WpD + 1 * 64 + cl * 4) * L2E;
    wp2 = *(const float4v*)(WpD + 2 * 64 + cl * 4) * L2E;
    float4v bpv = *(const float4v*)(bp + dd * 64 + cl * 4);
    float4v qf;
#pragma unroll
    for (int i = 0; i < 4; ++i) qf[i] = b2f(qh[i]);
    bq = qf + bpv * L2E;
    qorig = qf * LN2;
  }
  const char* KVb = (const char*)(kvp + (size_t)dd * NP * CH);

  // strength-reduced LDS walk: start at edge (half*8)<<dd, step (1<<dd)
  const float* ep = &sEdge[g * 260] + (((half * 8) << dd) * 4);
  const int estep = (1 << dd) * 4;          // floats per edge step

  float4v s    = {0.f, 0.f, 0.f, 0.f};
  float4v accv = {0.f, 0.f, 0.f, 0.f};
#pragma unroll
  for (int e = 0; e < 8; ++e) {
    float4v w = *(const float4v*)ep;
    ep += estep;
    uint4v u = *(const uint4v*)(KVb + (__float_as_uint(w[3]) + clOfs));
    float4v kf, vf, wgt;
#pragma unroll
    for (int i = 0; i < 4; ++i) kf[i] = __uint_as_float(u[i] & 0xFFFF0000u);
#pragma unroll
    for (int i = 0; i < 4; ++i) vf[i] = __uint_as_float(u[i] << 16);
    float4v t = bq + w[0] * wp0 + w[1] * wp1 + w[2] * wp2;  // q_s + delta_s
    float4v a = t - kf;
#pragma unroll
    for (int i = 0; i < 4; ++i) wgt[i] = __builtin_amdgcn_exp2f(a[i]);
    s += wgt;
    accv += wgt * (vf + t * LN2);           // w * (v + ln2*t)
  }

  // publish partials: P = accv - q*s  (q uniform across halves)
  float4v P = accv - qorig * s;
  *(float4v*)&sS[(wy * 4 + g) * 68 + cl * 4] = s;
  *(float4v*)&sP[(wy * 4 + g) * 68 + cl * 4] = P;
  __syncthreads();

  if (wy == 0) {                            // single combine wave
    float4v res;
#pragma unroll
    for (int d2 = 0; d2 < 3; ++d2) {
      float4v s0 = *(const float4v*)&sS[((d2    ) * 4 + g) * 68 + cl * 4];
      float4v s1 = *(const float4v*)&sS[((d2 + 3) * 4 + g) * 68 + cl * 4];
      float4v p0 = *(const float4v*)&sP[((d2    ) * 4 + g) * 68 + cl * 4];
      float4v p1 = *(const float4v*)&sP[((d2 + 3) * 4 + g) * 68 + cl * 4];
      float4v st = s0 + s1;
      float4v pt = p0 + p1;
      float4v r;
#pragma unroll
      for (int i = 0; i < 4; ++i)
        r[i] = pt[i] * __builtin_amdgcn_rcpf(st[i] + EPSF);
      if (d2 == 0) res = r;
      else {
#pragma unroll
        for (int i = 0; i < 4; ++i) res[i] = fmaxf(res[i], r[i]);
      }
    }
    const int b = node / PTS;
    const float* pp = poolP + (size_t)(b * PPB) * CH + cl * 4;
    float4v pv = *(const float4v*)pp;
#pragma unroll
    for (int q2 = 1; q2 < PPB; ++q2) {
      float4v t2 = *(const float4v*)(pp + (size_t)q2 * CH);
#pragma unroll
      for (int i = 0; i < 4; ++i) pv[i] = fmaxf(pv[i], t2[i]);
    }
    float4v xv = *(const float4v*)(x + (size_t)node * CH + cl * 4);
#pragma unroll
    for (int i = 0; i < 4; ++i) res[i] = fmaxf(res[i], pv[i]) + xv[i];
    *(float4v*)(out + (size_t)node * CH + cl * 4) = res;
  }
}

// ---------------------------------------------------------------------------
extern "C" void kernel_launch(void* const* d_in, const int* in_sizes, int n_in,
                              void* d_out, int out_size, void* d_ws, size_t ws_size,
                              hipStream_t stream) {
  const float* x    = (const float*)d_in[0];
  const float* pos  = (const float*)d_in[1];
  const float* Wv   = (const float*)d_in[2];
  const float* Wq   = (const float*)d_in[3];
  const float* Wk   = (const float*)d_in[4];
  const float* Wp   = (const float*)d_in[5];
  const float* bp   = (const float*)d_in[6];
  const int*   ei   = (const int*)d_in[7];
  float* out = (float*)d_out;

  char* wsb = (char*)d_ws;
  ushort* qbf   = (ushort*)wsb;
  unsigned int* kvp = (unsigned int*)(wsb + QBF_BYTES);
  ushort* wpack = (ushort*)(wsb + QBF_BYTES + KVP_BYTES);
  float*  poolP = (float*)(wsb + QBF_BYTES + KVP_BYTES +
                           (size_t)WPACK_ELEMS * 2);

  // 0) pool partials + W pack
  {
    int packBlocks = (WPACK_ELEMS + 255) / 256;
    dim3 grid(NB * PPB + packBlocks);
    hipLaunchKernelGGL(prep_kernel, grid, dim3(256), 0, stream,
                       x, Wv, Wq, Wk, wpack, poolP);
  }
  // 1) Q + packed KV via MFMA (1 block per 16-node tile, 6 waves = 6 slices)
  {
    dim3 grid(NTILES);
    dim3 block(64, 6);
    hipLaunchKernelGGL(qkv_mfma, grid, block, 0, stream, x, wpack, qbf, kvp);
  }
  // 2) fused attention + combine (exact round-0 version)
  {
    dim3 grid(8 * ((ATILES + 7) / 8));
    dim3 block(64, 6);
    hipLaunchKernelGGL(attn_kernel, grid, block, 0, stream,
                       x, pos, Wp, bp, ei, qbf, kvp, poolP, out);
  }
}